// Round 1
// 195.218 us; speedup vs baseline: 1.0027x; 1.0027x over previous
//
#include <hip/hip_runtime.h>
#include <math.h>
#include <float.h>

#define S 8192
#define D 64
#define N 2048
#define O 8

// Fused per-row logsumexp for all four weight matrices, ONE WAVE PER ROW.
// Block = 256 threads = 4 waves = 4 row-tasks. No LDS, no __syncthreads.
//   blocks [0, 512):        w0 rows (W=64):  row = b*4 + wave, lane i holds w0[row][i]
//   blocks [512, 1538):     wide rows (W=2048): task = (b-512)*4 + wave
//     task [0,N) -> w1 ; [N,2N) -> w2 ; [2N,2N+O) -> w_out
// ws layout (floats): lse0[0..N) lse1[N..2N) lse2[2N..3N) lseo[3N..3N+O)
__global__ __launch_bounds__(256) void lse_all_kernel(
    const float* __restrict__ w0, const float* __restrict__ w1,
    const float* __restrict__ w2, const float* __restrict__ w_out,
    float* __restrict__ ws) {
    int wave = threadIdx.x >> 6;
    int lane = threadIdx.x & 63;
    int b = blockIdx.x;

    float m, sum;
    float* out;
    int row;

    if (b < 512) {
        // w0: 64 floats per row, one float per lane, one 256B transaction.
        row = b * 4 + wave;
        m = w0[row * D + lane];
        sum = 1.0f;               // exp(v - v)
        out = ws;                 // lse0
    } else {
        int task = (b - 512) * 4 + wave;   // wave-uniform
        const float* w;
        if (task < N)          { w = w1;    row = task;         out = ws + N;     }
        else if (task < 2 * N) { w = w2;    row = task - N;     out = ws + 2 * N; }
        else                   { w = w_out; row = task - 2 * N; out = ws + 3 * N; }

        // 2048 floats per row = 512 float4; lane l takes indices l + 64k,
        // so each load instruction covers 1 KiB contiguous per wave.
        const float4* rp4 = (const float4*)(w + (size_t)row * N);
        float4 v[8];
        #pragma unroll
        for (int k = 0; k < 8; ++k) v[k] = rp4[lane + 64 * k];

        // max-then-sum: all loads independent, max tree, then 32 independent
        // exps -- no serial online-rescale chain.
        float mv = -FLT_MAX;
        #pragma unroll
        for (int k = 0; k < 8; ++k)
            mv = fmaxf(mv, fmaxf(fmaxf(v[k].x, v[k].y), fmaxf(v[k].z, v[k].w)));
        float s = 0.0f;
        #pragma unroll
        for (int k = 0; k < 8; ++k)
            s += __expf(v[k].x - mv) + __expf(v[k].y - mv)
               + __expf(v[k].z - mv) + __expf(v[k].w - mv);
        m = mv; sum = s;
    }

    // 64-lane butterfly online-LSE merge; every lane ends with the full state.
    #pragma unroll
    for (int off = 32; off >= 1; off >>= 1) {
        float mo = __shfl_xor(m, off, 64);
        float so = __shfl_xor(sum, off, 64);
        float nm = fmaxf(m, mo);
        sum = sum * __expf(m - nm) + so * __expf(mo - nm);
        m = nm;
    }
    if (lane == 0) out[row] = m + __logf(sum);
}

// One thread per (s, o). Walk the sampled path, accumulate log-prob, write
// out[0][s][o] = sin^3(x[s,cin]) and out[1][s][o] = exp(logp).
// (Unchanged: latency-bound on the forced keys->c2->c1->c0->x chain, ~3 us.)
__global__ __launch_bounds__(256) void path_gather_kernel(
    const float* __restrict__ x,
    const float* __restrict__ w0, const float* __restrict__ w1,
    const float* __restrict__ w2, const float* __restrict__ w_out,
    const int* __restrict__ c0, const int* __restrict__ c1,
    const int* __restrict__ c2, const int* __restrict__ keys_out,
    const float* __restrict__ ws, float* __restrict__ out) {
    int t = blockIdx.x * blockDim.x + threadIdx.x;
    int s = t >> 3;   // O == 8
    int o = t & 7;

    const float* lse0 = ws;
    const float* lse1 = ws + N;
    const float* lse2 = ws + 2 * N;
    const float* lseo = ws + 3 * N;

    int r2 = keys_out[t];                                 // [0, N)
    float logp = w_out[o * N + r2] - lseo[o];

    int r1 = c2[(size_t)s * N + r2];                      // [0, N)
    logp += w2[(size_t)r2 * N + r1] - lse2[r2];

    int r0 = c1[(size_t)s * N + r1];                      // [0, N)
    logp += w1[(size_t)r1 * N + r0] - lse1[r1];

    int cin = c0[(size_t)s * N + r0];                     // [0, D)
    logp += w0[r0 * D + cin] - lse0[r0];

    float y = sinf(sinf(sinf(x[s * D + cin])));

    out[t] = y;                    // output 0: y       [S*O]
    out[S * O + t] = __expf(logp); // output 1: probas  [S*O]
}

extern "C" void kernel_launch(void* const* d_in, const int* in_sizes, int n_in,
                              void* d_out, int out_size, void* d_ws, size_t ws_size,
                              hipStream_t stream) {
    const float* x      = (const float*)d_in[0];
    const float* w0     = (const float*)d_in[1];
    const float* w1     = (const float*)d_in[2];
    const float* w2     = (const float*)d_in[3];
    const float* w_out  = (const float*)d_in[4];
    const int*   c0     = (const int*)d_in[5];
    const int*   c1     = (const int*)d_in[6];
    const int*   c2     = (const int*)d_in[7];
    const int*   keys_o = (const int*)d_in[8];
    float* out = (float*)d_out;
    float* ws  = (float*)d_ws;   // 3N + O floats of lse scratch

    // Pass 1: per-row logsumexp, one wave per row.
    // 512 blocks (w0) + (2N + O)/4 = 1026 blocks (w1, w2, w_out) = 1538.
    lse_all_kernel<<<512 + (2 * N + O) / 4, 256, 0, stream>>>(w0, w1, w2, w_out, ws);

    // Pass 2: path walk + gather, one thread per (s, o).
    path_gather_kernel<<<(S * O) / 256, 256, 0, stream>>>(
        x, w0, w1, w2, w_out, c0, c1, c2, keys_o, ws, out);
}